// Round 5
// baseline (238.870 us; speedup 1.0000x reference)
//
#include <hip/hip_runtime.h>

typedef unsigned short ushort_t;
typedef unsigned int uint32;
typedef __attribute__((ext_vector_type(8))) short s16x8;   // 8 bf16 in 4 VGPRs
typedef __attribute__((ext_vector_type(4))) float f32x4;   // MFMA accumulator

#define BB   16
#define CC   256
#define NPX  4096          // 64*64 pixels
#define EE   4
#define HID  128
#define RHH  128

__device__ __forceinline__ ushort_t f2bf(float f) {
  uint32 x = __float_as_uint(f);
  x += 0x7fffu + ((x >> 16) & 1u);           // round-to-nearest-even
  return (ushort_t)(x >> 16);
}
// async global->LDS, 16B per lane; lds ptr wave-uniform (HW adds lane*16)
__device__ __forceinline__ void g2l16(const void* g, void* l) {
  __builtin_amdgcn_global_load_lds((const __attribute__((address_space(1))) uint32*)g,
                                   (__attribute__((address_space(3))) uint32*)l, 16, 0, 0);
}

// ---------- prep: pooling (direct, coalesced) + weight prep ----------
__global__ __launch_bounds__(256)
void k_prep(const float* __restrict__ x, float* __restrict__ pooled,
            const float* __restrict__ W1f, const float* __restrict__ W3f,
            const float* __restrict__ W2f, ushort_t* __restrict__ W1b,
            ushort_t* __restrict__ W3b, ushort_t* __restrict__ W2r) {
  int bid = blockIdx.x, t = threadIdx.x;
  if (bid < 4096) {           // pooling: one block per (b,c), 16KB contiguous read
    int c = bid & 255, b = bid >> 8;
    const float* xg = x + ((size_t)b * CC + c) * NPX;
    float s = 0.f;
#pragma unroll
    for (int k = 0; k < 4; ++k) {
      float4 v = *(const float4*)(xg + (size_t)(k * 256 + t) * 4);
      s += v.x + v.y + v.z + v.w;
    }
#pragma unroll
    for (int o = 32; o >= 1; o >>= 1) s += __shfl_down(s, o, 64);
    __shared__ float wsum[4];
    if ((t & 63) == 0) wsum[t >> 6] = s;
    __syncthreads();
    if (t == 0) pooled[(size_t)b * CC + c] = wsum[0] + wsum[1] + wsum[2] + wsum[3];
  } else if (bid < 4352) {    // W1/W3 convert, 4 elems/thread
    int i4 = ((bid - 4096) * 256 + t) * 4;
    const float* src; ushort_t* dst; int off;
    if (i4 < EE * HID * CC) { src = W1f; dst = W1b; off = i4; }
    else { src = W3f; dst = W3b; off = i4 - EE * HID * CC; }
    float4 v = *(const float4*)(src + off);
    ushort4 o;
    o.x = f2bf(v.x); o.y = f2bf(v.y); o.z = f2bf(v.z); o.w = f2bf(v.w);
    *(ushort4*)(dst + off) = o;
  } else {                    // W2 repack: contiguous 72B reads, u32 coalesced stores
    int idx = (bid - 4352) * 256 + t;     // 0..32767 = (e*128+o)*64 + ip/2
    int e = idx >> 13;
    int o = (idx >> 6) & 127;
    int ip = (idx & 63) * 2;
    const float* s0 = W2f + ((size_t)((e * 128 + o) * 128) + ip) * 9;
    float v0[9], v1[9];
#pragma unroll
    for (int tp = 0; tp < 9; ++tp) { v0[tp] = s0[tp]; v1[tp] = s0[9 + tp]; }
#pragma unroll
    for (int tp = 0; tp < 9; ++tp) {
      uint32 w = (uint32)f2bf(v0[tp]) | ((uint32)f2bf(v1[tp]) << 16);
      *(uint32*)&W2r[(((size_t)(e * 9 + tp) * 128 + o) * 128) + ip] = w;
    }
  }
}

// ---------- router: MLP + softmax + top-1 (fp32) ----------
__global__ __launch_bounds__(128)
void k_router(const float* __restrict__ pooled, const float* __restrict__ Wr1,
              const float* __restrict__ br1, const float* __restrict__ Wr2,
              const float* __restrict__ br2, int* __restrict__ eidx,
              float* __restrict__ gatew) {
  int b = blockIdx.x, t = threadIdx.x;
  __shared__ float spool[CC];
  __shared__ float hb[RHH];
  __shared__ float lg[EE];
  for (int cc = t; cc < CC; cc += 128) spool[cc] = pooled[(size_t)b * CC + cc];
  __syncthreads();
  float s0 = 0.f;
  const float* wr = Wr1 + t * CC;
  for (int c = 0; c < CC; ++c) s0 += spool[c] * wr[c];
  float a = br1[t] + s0 * (1.0f / NPX);
  hb[t] = a > 0.f ? a : 0.f;
  __syncthreads();
  if (t < EE) {
    float s = br2[t];
    const float* w2 = Wr2 + t * RHH;
    for (int r = 0; r < RHH; ++r) s += hb[r] * w2[r];
    lg[t] = s;
  }
  __syncthreads();
  if (t == 0) {
    float m = lg[0]; int mi = 0;
    for (int e = 1; e < EE; ++e) if (lg[e] > m) { m = lg[e]; mi = e; }  // first-max = lax.top_k tie rule
    float den = 0.f;
    for (int e = 0; e < EE; ++e) den += expf(lg[e] - m);
    float v = 1.0f / den;                 // softmax value at argmax
    eidx[b] = mi;
    gatew[b] = v / (v + 1e-9f);           // top-1 renormalized weight
  }
}

// weight-tile stage: 128 rows x 64 k from wsrc (row stride HID), k offset k0v.
// 16B chunks XOR-swizzled on the GLOBAL address side (LDS side is linear).
#define STAGEW(dst, wsrc, k0v)                                            \
  {                                                                       \
    _Pragma("unroll")                                                     \
    for (int s_ = 0; s_ < 4; ++s_) {                                      \
      int ch_ = wave * 4 + s_;                                            \
      int r_ = ch_ * 8 + (lane >> 3);                                     \
      int kc_ = ((lane & 7) ^ (lane >> 3)) * 8;                           \
      g2l16(wsrc + (size_t)r_ * HID + (k0v) + kc_, &dst[ch_ * 512]);      \
    }                                                                     \
  }

#define MFMA64(At_, Bt_, ACC_)                                            \
  _Pragma("unroll")                                                       \
  for (int kh = 0; kh < 2; ++kh) {                                        \
    s16x8 af[4], bfr[4];                                                  \
    int cidx = ((kh * 4 + (lane >> 4)) ^ (lane & 7)) * 8;                 \
    _Pragma("unroll")                                                     \
    for (int i = 0; i < 4; ++i)                                           \
      af[i] = *(const s16x8*)&At_[(wm + i * 16 + (lane & 15)) * 64 + cidx]; \
    _Pragma("unroll")                                                     \
    for (int j = 0; j < 4; ++j)                                           \
      bfr[j] = *(const s16x8*)&Bt_[(wn + j * 16 + (lane & 15)) * 64 + cidx]; \
    _Pragma("unroll")                                                     \
    for (int i = 0; i < 4; ++i)                                           \
      _Pragma("unroll")                                                   \
      for (int j = 0; j < 4; ++j)                                         \
        ACC_[i][j] = __builtin_amdgcn_mfma_f32_16x16x32_bf16(af[i], bfr[j], ACC_[i][j], 0, 0, 0); \
  }

// A from resident halo Hs[4][66][64] (pixel-major, chunk-XOR key = pixidx&7)
#define MFMA64H(Hs_, dyv, dxv, Bt_, ACC_)                                 \
  {                                                                       \
    int hbase = ((wm >> 6) + 1 + (dyv)) * 66 + (lane & 15) + 1 + (dxv);   \
    _Pragma("unroll")                                                     \
    for (int kh = 0; kh < 2; ++kh) {                                      \
      s16x8 af[4], bfr[4];                                                \
      int clog = kh * 4 + (lane >> 4);                                    \
      int aoff = (clog ^ (hbase & 7)) << 3;                               \
      int cidx = (clog ^ (lane & 7)) << 3;                                \
      _Pragma("unroll")                                                   \
      for (int i = 0; i < 4; ++i)                                         \
        af[i] = *(const s16x8*)&Hs_[(hbase + i * 16) * 64 + aoff];        \
      _Pragma("unroll")                                                   \
      for (int j = 0; j < 4; ++j)                                         \
        bfr[j] = *(const s16x8*)&Bt_[(wn + j * 16 + (lane & 15)) * 64 + cidx]; \
      _Pragma("unroll")                                                   \
      for (int i = 0; i < 4; ++i)                                         \
        _Pragma("unroll")                                                 \
        for (int j = 0; j < 4; ++j)                                       \
          ACC_[i][j] = __builtin_amdgcn_mfma_f32_16x16x32_bf16(af[i], bfr[j], ACC_[i][j], 0, 0, 0); \
    }                                                                     \
  }

// ---------- fused conv1 (1x1, halo recompute) + conv2 (3x3) + conv3 (1x1) ----------
// Per block: 4-padded-row window (256 contiguous x px). Per K-half kh:
//   conv1-half: 4 c-chunks {At 256px x 64c transpose-staged; W1 tile in Hs[0:8K);
//               MFMA M=256 N=64 K=64} -> relu+cvt -> swizzled Hs[4][66][64]
//   conv2 tap loop: R2-verbatim (dbuf W2 in At region, vmcnt(4))
// Then phase 2/3/4 verbatim R2 (y2s/Tf alias Hs; W3 tiles in At region).
__global__ __launch_bounds__(256, 2)
void k_fused(const float* __restrict__ x, const ushort_t* __restrict__ W1b,
             const ushort_t* __restrict__ W2r, const ushort_t* __restrict__ W3b,
             const int* __restrict__ eidx, const float* __restrict__ gatew,
             float* __restrict__ out) {
  int mt = blockIdx.x, b = blockIdx.y;
  int e = eidx[b];
  float gw = gatew[b];
  int t = threadIdx.x, wave = t >> 6, lane = t & 63;
  int wm = (wave & 1) * 64, wn = (wave >> 1) * 64;
  __shared__ ushort_t Hs[4 * 66 * 64];     // 33792 B: conv1 W1-tile(first 8K) -> y1 halo -> y2s/Tf
  __shared__ ushort_t WbA[2 * 128 * 64];   // 32768 B: conv1 At / W2 dbuf / W3 tiles
  ushort_t* Wb0 = WbA;
  ushort_t* Wb1 = WbA + 128 * 64;
  const ushort_t* w2e = W2r + (size_t)e * 9 * HID * HID;
  const float* xg = x + (size_t)b * CC * NPX;
  int px0 = mt * 128 - 64;                 // first real px of 4-row window (may be <0)
  int cp = t >> 3, kk = cp * 2, pxb = (t & 7) * 4;

  // ---- phase 1: per K-half {conv1 recompute -> Hs; conv2 taps} ----
  f32x4 acc[4][4] = {};
#pragma unroll 1
  for (int kh = 0; kh < 2; ++kh) {
    int k0 = kh * 64;
    // conv1-half: acc1 = x[4rows] . W1b[e][k0..k0+64)
    f32x4 acc1[4][4] = {};
    const ushort_t* w1h = W1b + ((size_t)e * HID + k0) * CC;
#pragma unroll 1
    for (int cc = 0; cc < 4; ++cc) {
      int c0 = cc * 64;
      __syncthreads();              // At/Bt (and at kh=1: Wb/Hs) readers done
      {   // stage W1 tile 64h x 64c -> Hs[0:8K), 512 chunks, 2/thread
#pragma unroll
        for (int s_ = 0; s_ < 2; ++s_) {
          int ch2 = wave * 128 + s_ * 64 + lane;
          int r_ = ch2 >> 3, slot = ch2 & 7;
          g2l16(w1h + (size_t)r_ * CC + c0 + ((slot ^ (r_ & 7)) << 3),
                &Hs[(wave * 128 + s_ * 64) * 8]);
        }
      }
      {   // At transpose: 2 c-rows x 32 px fp32 -> bf16x2 -> swizzled ds_write
        const float* r0 = xg + (size_t)(c0 + kk) * NPX + px0;
        const float* r1 = r0 + NPX;
#pragma unroll
        for (int i = 0; i < 8; ++i) {
          int p = pxb + i * 32;           // window px 0..255
          int rp = px0 + p;               // real px
          float4 va, vb;
          if (rp >= 0 && rp < NPX) { va = *(const float4*)(r0 + p); vb = *(const float4*)(r1 + p); }
          else { va = make_float4(0.f, 0.f, 0.f, 0.f); vb = va; }
#pragma unroll
          for (int q = 0; q < 4; ++q) {
            int m = p + q;
            uint32 v = (uint32)f2bf(((const float*)&va)[q]) |
                       ((uint32)f2bf(((const float*)&vb)[q]) << 16);
            int us = m * 64 + (((kk >> 3) ^ (m & 7)) << 3) + (kk & 7);
            *(uint32*)&WbA[us] = v;
          }
        }
      }
      __syncthreads();              // At written + W1 tile landed (vmcnt drained)
#pragma unroll
      for (int khk = 0; khk < 2; ++khk) {
        s16x8 af[4], bfr[4];
        int clog = khk * 4 + (lane >> 4);
        int cidx = (clog ^ (lane & 7)) * 8;
#pragma unroll
        for (int i = 0; i < 4; ++i)
          af[i] = *(const s16x8*)&WbA[(wave * 64 + i * 16 + (lane & 15)) * 64 + cidx];
#pragma unroll
        for (int j = 0; j < 4; ++j)
          bfr[j] = *(const s16x8*)&Hs[(j * 16 + (lane & 15)) * 64 + cidx];
#pragma unroll
        for (int i = 0; i < 4; ++i)
#pragma unroll
          for (int j = 0; j < 4; ++j)
            acc1[i][j] = __builtin_amdgcn_mfma_f32_16x16x32_bf16(af[i], bfr[j], acc1[i][j], 0, 0, 0);
      }
    }
    __syncthreads();                // all conv1 MFMA LDS reads done (At+W1 free)
    STAGEW(Wb0, w2e, k0);           // prefetch W2 tap0 into freed At region
    // relu+cvt acc1 -> swizzled Hs halo (wave owns window px [wave*64, wave*64+64))
#pragma unroll
    for (int i = 0; i < 4; ++i)
#pragma unroll
      for (int j = 0; j < 4; ++j)
#pragma unroll
        for (int r = 0; r < 4; ++r) {
          int m = wave * 64 + i * 16 + (lane >> 4) * 4 + r;   // window px
          int h = j * 16 + (lane & 15);                       // ch within half
          int pix = (m >> 6) * 66 + (m & 63) + 1;
          float v = acc1[i][j][r];
          Hs[pix * 64 + (((h >> 3) ^ (pix & 7)) << 3) + (h & 7)] = f2bf(v > 0.f ? v : 0.f);
        }
    {   // zero pad columns: 8 pixel-rows (col 0 and 65 of 4 window rows) x 64 ch
      int row8 = t >> 5;            // 0..7
      int pix = (row8 >> 1) * 66 + (row8 & 1) * 65;
      ((uint32*)&Hs[pix * 64])[t & 31] = 0u;
    }
    __syncthreads();                // Hs complete + W2 tap0 landed
    // conv2 tap loop (R2 verbatim)
#pragma unroll
    for (int tap = 0; tap < 9; ++tap) {
      ushort_t* cur = (tap & 1) ? Wb1 : Wb0;
      ushort_t* nxt = (tap & 1) ? Wb0 : Wb1;
      if (tap < 8) {
        STAGEW(nxt, w2e + (size_t)(tap + 1) * HID * HID, k0);
        asm volatile("s_waitcnt vmcnt(4)" ::: "memory");   // my tap tile landed
      } else {
        asm volatile("s_waitcnt vmcnt(0)" ::: "memory");   // drain last tile
      }
      __builtin_amdgcn_s_barrier();                        // everyone's landed
      MFMA64H(Hs, tap / 3 - 1, tap % 3 - 1, cur, acc);
      __builtin_amdgcn_s_barrier();                        // reads done before overwrite
    }
  }
  // ---- phase 2: relu+cvt -> swizzled y2 LDS tile (aliases Hs; reads all done) ----
  __syncthreads();
  ushort_t (*y2s)[128 * 64] = (ushort_t (*)[128 * 64])Hs;
#pragma unroll
  for (int i = 0; i < 4; ++i)
#pragma unroll
    for (int j = 0; j < 4; ++j)
#pragma unroll
      for (int r = 0; r < 4; ++r) {
        int m = wm + i * 16 + (lane >> 4) * 4 + r;
        int n = wn + j * 16 + (lane & 15);
        float v = acc[i][j][r];
        ushort_t bv = f2bf(v > 0.f ? v : 0.f);
        int nn = n & 63;
        ushort_t* buf = (n < 64) ? y2s[0] : y2s[1];   // wave-uniform select
        buf[m * 64 + ((nn >> 3) ^ (m & 7)) * 8 + (nn & 7)] = bv;
      }
  // ---- phase 3: conv3, both 128-c halves, K=128 from y2s ----
  f32x4 acc3[2][4][4] = {};
  const ushort_t* w3 = W3b + (size_t)e * CC * HID;
#pragma unroll
  for (int h = 0; h < 2; ++h) {
#pragma unroll
    for (int ks = 0; ks < 2; ++ks) {
      ushort_t* bt = (ks == 0) ? Wb0 : Wb1;
      STAGEW(bt, w3 + (size_t)(h * 128) * HID, ks * 64);
      __syncthreads();          // drains stage + makes y2s writes visible
      MFMA64(y2s[ks], bt, acc3[h]);
      // next STAGEW overwrites only after all waves passed the barrier above,
      // and each wave's LDS reads complete before its own MFMAs -> WAR safe
    }
  }
  // ---- phase 4: coalesced epilogue, Tf aliases Hs (dead now) ----
  float* Tf = (float*)Hs;   // 32c x 128px, pitch 132 (16.9 KB)
  for (int h = 0; h < 2; ++h) {
    for (int jj = 0; jj < 4; ++jj) {
      __syncthreads();
      if ((wn >> 6) == (jj >> 1)) {     // the 2 waves holding this c-range
        int j0 = (jj & 1) * 2;
#pragma unroll
        for (int jd = 0; jd < 2; ++jd) {
          int cl = jd * 16 + (lane & 15);
#pragma unroll
          for (int i = 0; i < 4; ++i) {
            int pb = wm + i * 16 + (lane >> 4) * 4;
            *(f32x4*)&Tf[cl * 132 + pb] = acc3[h][i][j0 + jd];
          }
        }
      }
      __syncthreads();
#pragma unroll
      for (int it = 0; it < 4; ++it) {
        int idx = it * 256 + t;          // 0..1023
        int crow = idx >> 5;             // 0..31
        int p4 = (idx & 31) * 4;
        int c = h * 128 + jj * 32 + crow;
        int px = mt * 128 + p4;
        size_t base = ((size_t)b * CC + c) * NPX + px;
        f32x4 vv = *(const f32x4*)&Tf[crow * 132 + p4];
        f32x4 xa = *(const f32x4*)(x + base);
        vv = gw * vv + xa;
        __builtin_nontemporal_store(vv, (f32x4*)(out + base));
      }
    }
  }
}

extern "C" void kernel_launch(void* const* d_in, const int* in_sizes, int n_in,
                              void* d_out, int out_size, void* d_ws, size_t ws_size,
                              hipStream_t stream) {
  const float* x   = (const float*)d_in[0];
  const float* Wr1 = (const float*)d_in[1];
  const float* br1 = (const float*)d_in[2];
  const float* Wr2 = (const float*)d_in[3];
  const float* br2 = (const float*)d_in[4];
  const float* W1  = (const float*)d_in[5];
  const float* W2  = (const float*)d_in[6];
  const float* W3  = (const float*)d_in[7];
  float* out = (float*)d_out;

  char* ws = (char*)d_ws;
  int*      eidx   = (int*)ws;                         // 64 B
  float*    gatew  = (float*)(ws + 64);                // 64 B -> 256
  float*    pooled = (float*)(ws + 256);               // 16 KB -> 16640
  ushort_t* W1b    = (ushort_t*)(ws + 16640);          // 256 KB -> 278784
  ushort_t* W3b    = (ushort_t*)(ws + 278784);         // 256 KB -> 540928
  ushort_t* W2r    = (ushort_t*)(ws + 540928);         // 1.125 MB -> ~1.7 MB total

  k_prep  <<<4480, 256, 0, stream>>>(x, pooled, W1, W3, W2, W1b, W3b, W2r);
  k_router<<<16, 128, 0, stream>>>(pooled, Wr1, br1, Wr2, br2, eidx, gatew);
  k_fused <<<dim3(32, 16), 256, 0, stream>>>(x, W1b, W2r, W3b, eidx, gatew, out);
}